// Round 18
// baseline (466.100 us; speedup 1.0000x reference)
//
#include <hip/hip_runtime.h>

typedef __attribute__((ext_vector_type(8))) short short8;
typedef __attribute__((ext_vector_type(4))) float f32x4;
typedef __attribute__((ext_vector_type(16))) float f32x16;
typedef __attribute__((ext_vector_type(4))) unsigned short ushort4v;
typedef __attribute__((ext_vector_type(4))) unsigned u32x4;

#define S_LEN 2048
#define E_DIM 5120
#define NH 32
#define NKVH 8
#define HD 160
#define QKV_OUT (NH*HD + 2*NKVH*HD)   // 7680
#define NPAIR 20
#define ROT_D 40

__device__ __forceinline__ unsigned short f2b(float f) {
  unsigned u = __builtin_bit_cast(unsigned, f);
  u += 0x7fffu + ((u >> 16) & 1u);
  return (unsigned short)(u >> 16);
}
__device__ __forceinline__ float b2f(unsigned short b) {
  return __builtin_bit_cast(float, ((unsigned)b) << 16);
}

typedef const __attribute__((address_space(1))) unsigned gu32;
typedef __attribute__((address_space(3))) unsigned lu32;
__device__ __forceinline__ void gll16(const void* g, void* l) {
  __builtin_amdgcn_global_load_lds((gu32*)g, (lu32*)l, 16, 0, 0);
}
#define MFMA16(a, b, c) __builtin_amdgcn_mfma_f32_16x16x32_bf16(a, b, c, 0, 0, 0)
#define MFMA32(a, b, c) __builtin_amdgcn_mfma_f32_32x32x16_bf16(a, b, c, 0, 0, 0)
#define SBAR() asm volatile("s_barrier" ::: "memory")

// ---------------- prep: all three fp32 -> bf16 converts in ONE dispatch ----------------
__device__ __forceinline__ void cvt_seg(const float* __restrict__ in,
                                        unsigned short* __restrict__ out,
                                        long n4, long i0, long stride) {
  for (long i = i0; i < n4; i += stride) {
    float4 v = ((const float4*)in)[i];
    ushort4v o = { f2b(v.x), f2b(v.y), f2b(v.z), f2b(v.w) };
    ((ushort4v*)out)[i] = o;
  }
}
__global__ __launch_bounds__(256) void f32_to_bf16_all(const float* __restrict__ h,
                                                       const float* __restrict__ wq,
                                                       const float* __restrict__ wo,
                                                       unsigned short* __restrict__ hB,
                                                       unsigned short* __restrict__ wqB,
                                                       unsigned short* __restrict__ woB) {
  long i0 = (long)blockIdx.x * blockDim.x + threadIdx.x;
  long stride = (long)gridDim.x * blockDim.x;
  cvt_seg(h, hB, (long)S_LEN * E_DIM / 4, i0, stride);
  cvt_seg(wq, wqB, (long)QKV_OUT * E_DIM / 4, i0, stride);
  cvt_seg(wo, woB, (long)E_DIM * E_DIM / 4, i0, stride);
}

// ---------------- prep: cos/sin tables ----------------
__global__ __launch_bounds__(256) void build_trig(const int* __restrict__ positions,
                                                  float* __restrict__ cosT,
                                                  float* __restrict__ sinT) {
  int idx = blockIdx.x * blockDim.x + threadIdx.x;
  if (idx >= S_LEN * NPAIR) return;
  int s = idx / NPAIR, i = idx - s * NPAIR;
  float inv = powf(10000.0f, -(float)i / (float)NPAIR);
  float f = (float)positions[s] * inv;
  cosT[idx] = cosf(f);
  sinT[idx] = sinf(f);
}

// ---------------- 256x128 1-phase bf16 NT GEMM (BK=32, tri-buffer, 2 blocks/CU) ----------------
// 480 blocks (bm=bid&7=XCD, bn=bid>>3), 256 thr = 4 waves (2M x 2N, wave 128x64).
// LDS 72KB: LA[3][256x32] + LB[3][128x32] -> 2 blocks/CU co-resident: while one
// block's waves convoy at a barrier, the other feeds the LDS/MFMA pipes (TLP).
// Per tile t (buf=t%3): {12 ds_read (A8+B4); stage t+2 (6 gll) -> (t+2)%3 (last
// read at t-1, freed); 32 MFMA16; vmcnt(6) [drains t+1]; SBAR}. Depth-2, FIFO-
// exact; tails vmcnt(0). Swizzle: slot^=(row&3), both-sides (src pre-swizzled).
template <bool BIAS, bool OUT_BF16>
__global__ __launch_bounds__(256, 2) void gemm8(const unsigned short* __restrict__ A,
                                                const unsigned short* __restrict__ B,
                                                const float* __restrict__ bias,
                                                void* __restrict__ Cp,
                                                int N) {
  constexpr int K = E_DIM;
  constexpr int NT = K / 32;  // 160
  int bid = blockIdx.x;
  int bm = bid & 7, bn = bid >> 3;
  int tid = threadIdx.x;
  int l = tid & 63;
  int w = tid >> 6;
  int g = l >> 4, c = l & 15;
  int wm = w >> 1, wn = w & 1;

  __shared__ __align__(16) unsigned short LA[3][8192];  // 3 x 16KB (256 rows x 32)
  __shared__ __align__(16) unsigned short LB[3][4096];  // 3 x 8KB  (128 rows x 32)

  f32x4 acc[8][4];
#pragma unroll
  for (int i = 0; i < 8; ++i)
#pragma unroll
    for (int j = 0; j < 4; ++j) acc[i][j] = f32x4{0.f, 0.f, 0.f, 0.f};

  // staging bases (pre-swizzled source): unit u -> row=u>>2, slot=u&3,
  // src col = (slot^(row&3))*8 elems; LDS dst = u*16B (linear, DMA-friendly).
  const unsigned short* Ag[4];
#pragma unroll
  for (int j = 0; j < 4; ++j) {
    int u = j * 256 + tid;
    int row = u >> 2, sl = u & 3;
    Ag[j] = A + (size_t)(bm * 256 + row) * K + (sl ^ (row & 3)) * 8;
  }
  const unsigned short* Bg[2];
#pragma unroll
  for (int j = 0; j < 2; ++j) {
    int u = j * 256 + tid;
    int row = u >> 2, sl = u & 3;
    Bg[j] = B + (size_t)(bn * 128 + row) * K + (sl ^ (row & 3)) * 8;
  }

  auto stage = [&](int t, int buf) {
#pragma unroll
    for (int j = 0; j < 4; ++j)
      gll16(Ag[j] + t * 32, (char*)&LA[buf][0] + (j * 256 + tid) * 16);
#pragma unroll
    for (int j = 0; j < 2; ++j)
      gll16(Bg[j] + t * 32, (char*)&LB[buf][0] + (j * 256 + tid) * 16);
  };

  // ds_read offsets (shorts): row*32 + (g^(row&3))*8 ; frag rows == c mod 4.
  int aBase = (wm * 128 + c) * 32 + ((g ^ (c & 3)) * 8);
  int bBase = (wn * 64 + c) * 32 + ((g ^ (c & 3)) * 8);

  stage(0, 0);
  stage(1, 1);
  asm volatile("s_waitcnt vmcnt(6)" ::: "memory");
  SBAR();

  int cur = 0;
  for (int t = 0; t < NT; ++t) {
    const unsigned short* la = &LA[cur][0];
    const unsigned short* lb = &LB[cur][0];
    int nxt = (cur + 2 >= 3) ? cur - 1 : cur + 2;  // (t+2)%3

    short8 a[8], b[4];
#pragma unroll
    for (int fm = 0; fm < 8; ++fm) a[fm] = *(const short8*)&la[aBase + fm * 512];
#pragma unroll
    for (int fn = 0; fn < 4; ++fn) b[fn] = *(const short8*)&lb[bBase + fn * 512];
    if (t + 2 < NT) stage(t + 2, nxt);
    __builtin_amdgcn_s_setprio(1);
#pragma unroll
    for (int fm = 0; fm < 8; ++fm)
#pragma unroll
      for (int fn = 0; fn < 4; ++fn)
        acc[fm][fn] = MFMA16(a[fm], b[fn], acc[fm][fn]);
    __builtin_amdgcn_s_setprio(0);
    if (t + 2 < NT)
      asm volatile("s_waitcnt vmcnt(6)" ::: "memory");
    else
      asm volatile("s_waitcnt vmcnt(0)" ::: "memory");
    SBAR();
    cur = (cur == 2) ? 0 : cur + 1;
  }

  // ---- epilogue
#pragma unroll
  for (int FN = 0; FN < 4; ++FN) {
    int n = bn * 128 + wn * 64 + FN * 16 + c;
    float bv = BIAS ? bias[n] : 0.f;
#pragma unroll
    for (int FM = 0; FM < 8; ++FM) {
#pragma unroll
      for (int r = 0; r < 4; ++r) {
        int m = bm * 256 + wm * 128 + FM * 16 + 4 * g + r;
        float v = acc[FM][FN][r] + bv;
        if (OUT_BF16)
          ((unsigned short*)Cp)[(size_t)m * N + n] = f2b(v);
        else
          ((float*)Cp)[(size_t)m * N + n] = v;
      }
    }
  }
}

// ---------------- 256x160 2-phase bf16 NT GEMM (r13-proven, unchanged: grid==CU count) ----------------
__global__ __launch_bounds__(512, 2) void gemm160(const unsigned short* __restrict__ A,
                                                  const unsigned short* __restrict__ B,
                                                  float* __restrict__ C) {
  constexpr int K = E_DIM;
  constexpr int NT = K / 64;
  int bid = blockIdx.x;
  int bm = bid & 7, bn = bid >> 3;
  int tid = threadIdx.x;
  int w = tid >> 6, l = tid & 63;
  int g = l >> 4, c = l & 15;
  int wm = w >> 1, wn = w & 1;

  __shared__ __align__(16) unsigned short LA[2][2][8192];   // 64KB
  __shared__ __align__(16) unsigned short LB[2][20 * 512];  // 40KB

  f32x4 acc[4][5];
#pragma unroll
  for (int i = 0; i < 4; ++i)
#pragma unroll
    for (int j = 0; j < 5; ++j) acc[i][j] = f32x4{0.f, 0.f, 0.f, 0.f};

  int uU[2] = {tid, 512 + tid};
  const unsigned short* Ag[2];
#pragma unroll
  for (int j = 0; j < 2; ++j) {
    int u = uU[j];
    int wmG = u >> 9, rlA = (u >> 3) & 63, sl = u & 7;
    Ag[j] = A + (size_t)(bm * 256 + wmG * 128 + rlA) * K + (sl ^ (rlA & 7)) * 8;
  }
  auto stageA = [&](int t, int rg, int db) {
#pragma unroll
    for (int j = 0; j < 2; ++j)
      gll16(Ag[j] + (size_t)rg * 64 * K + t * 64, (char*)&LA[db][rg][0] + uU[j] * 16);
  };

  int rowin = l >> 3, slb = l & 7;
  int swz = (slb ^ rowin) * 8;
  int chN01 = (w < 4) ? w : 6 + w;
  int chN23 = (w < 4) ? 4 + w : 10 + w;
  int chN4 = (w < 2) ? 8 + w : 16 + w;
  const unsigned short* srcN01 = B + (size_t)(bn * 160 + chN01 * 8 + rowin) * K + swz;
  const unsigned short* srcN23 = B + (size_t)(bn * 160 + chN23 * 8 + rowin) * K + swz;
  const unsigned short* srcN4 = B + (size_t)(bn * 160 + ((w < 4) ? chN4 * 8 : 0) + rowin) * K + swz;
  auto stB = [&](const unsigned short* src, int ch, int t, int db) {
    gll16(src + t * 64, (char*)&LB[db][0] + ch * 1024 + l * 16);
  };

  int rgA = wm & 1;
  int aA = ((wm >> 1) * 64 + c) * 64;
  int bB = (wn * 80 + c) * 64;
  int s0 = (g ^ (c & 7)) * 8;
  int s1 = ((4 + g) ^ (c & 7)) * 8;

  short8 a[8], b01[4], b23[4], bn4[2];

  stageA(0, 0, 0); stageA(0, 1, 0);
  stB(srcN01, chN01, 0, 0); stB(srcN23, chN23, 0, 0);
  if (w < 4) stB(srcN4, chN4, 0, 0);
  stageA(1, 0, 1); stageA(1, 1, 1);
  stB(srcN01, chN01, 1, 1); stB(srcN23, chN23, 1, 1);
  asm volatile("s_waitcnt vmcnt(0)" ::: "memory");
  SBAR();

  for (int t = 0; t < NT; ++t) {
    int db = t & 1;
    const unsigned short* la = &LA[db][rgA][0];
    const unsigned short* lb = &LB[db][0];
    bool tail = (t + 2 >= NT);

    // ---- P1
#pragma unroll
    for (int fm = 0; fm < 4; ++fm) {
      a[2 * fm + 0] = *(const short8*)&la[aA + fm * 1024 + s0];
      a[2 * fm + 1] = *(const short8*)&la[aA + fm * 1024 + s1];
    }
#pragma unroll
    for (int fn = 0; fn < 2; ++fn) {
      b01[2 * fn + 0] = *(const short8*)&lb[bB + fn * 1024 + s0];
      b01[2 * fn + 1] = *(const short8*)&lb[bB + fn * 1024 + s1];
      b23[2 * fn + 0] = *(const short8*)&lb[bB + (2 + fn) * 1024 + s0];
      b23[2 * fn + 1] = *(const short8*)&lb[bB + (2 + fn) * 1024 + s1];
    }
    if (t + 1 < NT && w < 4) stB(srcN4, chN4, t + 1, db ^ 1);
    __builtin_amdgcn_s_setprio(1);
#pragma unroll
    for (int fm = 0; fm < 4; ++fm)
#pragma unroll
      for (int fn = 0; fn < 2; ++fn) {
        acc[fm][fn] = MFMA16(a[2 * fm + 0], b01[2 * fn + 0], acc[fm][fn]);
        acc[fm][fn] = MFMA16(a[2 * fm + 1], b01[2 * fn + 1], acc[fm][fn]);
        acc[fm][fn + 2] = MFMA16(a[2 * fm + 0], b23[2 * fn + 0], acc[fm][fn + 2]);
        acc[fm][fn + 2] = MFMA16(a[2 * fm + 1], b23[2 * fn + 1], acc[fm][fn + 2]);
      }
    __builtin_amdgcn_s_setprio(0);
    SBAR();

    // ---- P2
    bn4[0] = *(const short8*)&lb[bB + 4 * 1024 + s0];
    bn4[1] = *(const short8*)&lb[bB + 4 * 1024 + s1];
    if (!tail) {
      stageA(t + 2, 0, db); stageA(t + 2, 1, db);
      stB(srcN01, chN01, t + 2, db);
      stB(srcN23, chN23, t + 2, db);
    }
    __builtin_amdgcn_s_setprio(1);
#pragma unroll
    for (int fm = 0; fm < 4; ++fm) {
      acc[fm][4] = MFMA16(a[2 * fm + 0], bn4[0], acc[fm][4]);
      acc[fm][4] = MFMA16(a[2 * fm + 1], bn4[1], acc[fm][4]);
    }
    __builtin_amdgcn_s_setprio(0);
    if (tail)
      asm volatile("s_waitcnt vmcnt(0)" ::: "memory");
    else
      asm volatile("s_waitcnt vmcnt(6)" ::: "memory");
    SBAR();
  }

  // ---- epilogue (fp32)
#pragma unroll
  for (int fn = 0; fn < 5; ++fn) {
    int n = bn * 160 + wn * 80 + fn * 16 + c;
#pragma unroll
    for (int fm = 0; fm < 4; ++fm) {
#pragma unroll
      for (int r = 0; r < 4; ++r) {
        int m = bm * 256 + wm * 64 + fm * 16 + 4 * g + r;
        C[(size_t)m * E_DIM + n] = acc[fm][fn][r];
      }
    }
  }
}

// ---------------- rope (Q,K only; vectorized non-rot copy) ----------------
__global__ __launch_bounds__(256) void rope_qk(const unsigned short* __restrict__ qkv,
                                               const float* __restrict__ cosT,
                                               const float* __restrict__ sinT,
                                               unsigned short* __restrict__ Q,
                                               unsigned short* __restrict__ K) {
  int s = blockIdx.x;
  int tid = threadIdx.x;
  const unsigned short* row = qkv + (size_t)s * QKV_OUT;
  const float* cs = cosT + s * NPAIR;
  const float* sn = sinT + s * NPAIR;
  for (int p = tid; p < 40 * NPAIR; p += 256) {
    int head = p / NPAIR, i = p - head * NPAIR;
    float x1 = b2f(row[head * HD + i]);
    float x2 = b2f(row[head * HD + i + NPAIR]);
    float o1 = x1 * cs[i] - x2 * sn[i];
    float o2 = x2 * cs[i] + x1 * sn[i];
    unsigned short* dst = (head < NH) ? (Q + ((size_t)head * S_LEN + s) * HD)
                                      : (K + ((size_t)(head - NH) * S_LEN + s) * HD);
    dst[i] = f2b(o1);
    dst[i + NPAIR] = f2b(o2);
  }
  for (int u = tid; u < 40 * 15; u += 256) {
    int head = u / 15;
    int d8 = ROT_D + (u - head * 15) * 8;
    short8 v = *(const short8*)(row + head * HD + d8);
    unsigned short* dst = (head < NH) ? (Q + ((size_t)head * S_LEN + s) * HD)
                                      : (K + ((size_t)(head - NH) * S_LEN + s) * HD);
    *(short8*)(dst + d8) = v;
  }
}

// ---------------- V transpose: qkv -> Vt[kvh][d][s] ----------------
__global__ __launch_bounds__(256) void v_transpose(const unsigned short* __restrict__ qkv,
                                                   unsigned short* __restrict__ Vt) {
  int st = blockIdx.x;
  int kvh = blockIdx.y;
  int tid = threadIdx.x;
  __shared__ __align__(16) unsigned short T[64][168];
  const unsigned short* src = qkv + (size_t)(st * 64) * QKV_OUT + NH * HD + NKVH * HD + kvh * HD;
#pragma unroll
  for (int i = 0; i < 5; ++i) {
    int u = tid + i * 256;
    int r = u / 20, sl = u - r * 20;
    int4 val = *(const int4*)(src + (size_t)r * QKV_OUT + sl * 8);
    *(int4*)((char*)&T[r][0] + sl * 16) = val;
  }
  __syncthreads();
  unsigned short* dst = Vt + (size_t)kvh * HD * S_LEN + st * 64;
#pragma unroll
  for (int i = 0; i < 5; ++i) {
    int u = tid + i * 256;
    int d = u >> 3, sc = u & 7;
    unsigned short tmp[8];
#pragma unroll
    for (int j = 0; j < 8; ++j) tmp[j] = T[sc * 8 + j][d];
    *(int4*)(dst + (size_t)d * S_LEN + sc * 8) = *(const int4*)tmp;
  }
}

// ---------------- flash causal GQA attention, 32x32 MFMA, in-register P ----------------
// kvh = bid&7 == XCD (K/V L2-resident); strip = sidx<32 ? 63-sidx : sidx-32 so
// co-resident pair (bid, bid+256) is complementary (65 tiles per CU).
__global__ __launch_bounds__(256, 1) void attn_kernel(const unsigned short* __restrict__ Q,
                                                      const unsigned short* __restrict__ K,
                                                      const unsigned short* __restrict__ Vt,
                                                      unsigned short* __restrict__ Ao) {
  int bid = blockIdx.x;
  int kvh = bid & 7;
  int sidx = bid >> 3;
  int strip = (sidx < 32) ? (63 - sidx) : (sidx - 32);
  int nt = strip + 1;
  int qbase = strip * 32;
  int tid = threadIdx.x;
  int w = tid >> 6, l = tid & 63;
  int lo5 = l & 31, hi = l >> 5;
  int h = kvh * 4 + w;

  __shared__ __align__(16) unsigned short KL[2][10 * 512];
  __shared__ __align__(16) unsigned short VL[2][10 * 512];

  const unsigned short* kg = K + (size_t)kvh * S_LEN * HD;
  const unsigned short* vg = Vt + (size_t)kvh * HD * S_LEN;
  const unsigned short* qg = Q + ((size_t)h * S_LEN + qbase + lo5) * HD;

  short8 qf[10];
#pragma unroll
  for (int f = 0; f < 10; ++f) qf[f] = *(const short8*)(qg + f * 16 + hi * 8);

  auto STAGE = [&](int t, int buf) {
#pragma unroll
    for (int i = 0; i < 5; ++i) {
      int cc = w * 5 + i;
      if (cc < 10) {
        gll16(kg + ((size_t)(t * 32) + lo5) * HD + cc * 16 + hi * 8,
              (void*)&KL[buf][cc * 512]);
      } else {
        int m = cc - 10;
        int dblk = m >> 1, half = m & 1;
        gll16(vg + (size_t)(dblk * 32 + lo5) * S_LEN + t * 32 + half * 16 + hi * 8,
              (void*)&VL[buf][m * 512]);
      }
    }
  };

  const float sm_scale = 0.07905694150420949f;  // 160^-0.5
  f32x16 acc[5];
#pragma unroll
  for (int d = 0; d < 5; ++d)
#pragma unroll
    for (int r = 0; r < 16; ++r) acc[d][r] = 0.f;
  float l_run = 0.f;

  STAGE(0, 0);
  if (nt > 1) STAGE(1, 1);

#pragma unroll 1
  for (int t = 0; t < nt; ++t) {
    int buf = t & 1;
    if (t + 1 < nt)
      asm volatile("s_waitcnt vmcnt(5)" ::: "memory");
    else
      asm volatile("s_waitcnt vmcnt(0)" ::: "memory");
    SBAR();

    f32x16 S;
#pragma unroll
    for (int r = 0; r < 16; ++r) S[r] = 0.f;
    __builtin_amdgcn_s_setprio(1);
#pragma unroll
    for (int f = 0; f < 10; ++f) {
      short8 kf = *(const short8*)&KL[buf][f * 512 + l * 8];
      S = MFMA32(kf, qf[f], S);
    }
    __builtin_amdgcn_s_setprio(0);

    float e[16];
    float rsum = 0.f;
    if (t == nt - 1) {
#pragma unroll
      for (int r = 0; r < 16; ++r) {
        int kvloc = (r & 3) + 8 * (r >> 2) + 4 * hi;
        float x = (kvloc <= lo5) ? S[r] * sm_scale : -1e30f;
        e[r] = __expf(x);
        rsum += e[r];
      }
    } else {
#pragma unroll
      for (int r = 0; r < 16; ++r) {
        e[r] = __expf(S[r] * sm_scale);
        rsum += e[r];
      }
    }
    rsum += __shfl_xor(rsum, 32);
    l_run += rsum;

    unsigned xp[8];
#pragma unroll
    for (int i = 0; i < 8; ++i)
      asm("v_cvt_pk_bf16_f32 %0, %1, %2" : "=v"(xp[i]) : "v"(e[2 * i]), "v"(e[2 * i + 1]));
    asm volatile("v_permlane32_swap_b32 %0, %1" : "+v"(xp[0]), "+v"(xp[2]));
    asm volatile("v_permlane32_swap_b32 %0, %1" : "+v"(xp[1]), "+v"(xp[3]));
    asm volatile("v_permlane32_swap_b32 %0, %1" : "+v"(xp[4]), "+v"(xp[6]));
    asm volatile("v_permlane32_swap_b32 %0, %1" : "+v"(xp[5]), "+v"(xp[7]));
    u32x4 w0 = {xp[0], xp[1], xp[2], xp[3]};
    u32x4 w1 = {xp[4], xp[5], xp[6], xp[7]};
    short8 pa0 = __builtin_bit_cast(short8, w0);
    short8 pa1 = __builtin_bit_cast(short8, w1);

    __builtin_amdgcn_s_setprio(1);
#pragma unroll
    for (int dblk = 0; dblk < 5; ++dblk) {
      short8 v0 = *(const short8*)&VL[buf][(2 * dblk + 0) * 512 + l * 8];
      short8 v1 = *(const short8*)&VL[buf][(2 * dblk + 1) * 512 + l * 8];
      acc[dblk] = MFMA32(pa0, v0, acc[dblk]);
      acc[dblk] = MFMA32(pa1, v1, acc[dblk]);
    }
    __builtin_amdgcn_s_setprio(0);
    SBAR();
    if (t + 2 < nt) STAGE(t + 2, buf);
  }

  float rinv = 1.f / l_run;
  float ri[16];
#pragma unroll
  for (int r = 0; r < 16; ++r) ri[r] = __shfl(rinv, (r & 3) + 8 * (r >> 2) + 4 * hi);
#pragma unroll
  for (int dblk = 0; dblk < 5; ++dblk)
#pragma unroll
    for (int r = 0; r < 16; ++r) {
      int q = (r & 3) + 8 * (r >> 2) + 4 * hi;
      Ao[(size_t)(qbase + q) * E_DIM + h * HD + dblk * 32 + lo5] = f2b(acc[dblk][r] * ri[r]);
    }
}

// ---------------- launch ----------------
extern "C" void kernel_launch(void* const* d_in, const int* in_sizes, int n_in,
                              void* d_out, int out_size, void* d_ws, size_t ws_size,
                              hipStream_t stream) {
  const float* hidden = (const float*)d_in[0];
  const int* positions = (const int*)d_in[1];
  const float* w_qkv = (const float*)d_in[2];
  const float* b_qkv = (const float*)d_in[3];
  const float* w_o = (const float*)d_in[4];
  float* out = (float*)d_out;

  char* ws = (char*)d_ws;
  size_t off = 0;
  auto alloc = [&](size_t bytes) {
    void* p = ws + off;
    off += (bytes + 255) & ~(size_t)255;
    return p;
  };
  unsigned short* hB = (unsigned short*)alloc((size_t)S_LEN * E_DIM * 2);
  unsigned short* wqkvB = (unsigned short*)alloc((size_t)QKV_OUT * E_DIM * 2);
  unsigned short* woB = (unsigned short*)alloc((size_t)E_DIM * E_DIM * 2);
  unsigned short* qkvB = (unsigned short*)alloc((size_t)S_LEN * QKV_OUT * 2);
  unsigned short* Qb = (unsigned short*)alloc((size_t)NH * S_LEN * HD * 2);
  unsigned short* Kb = (unsigned short*)alloc((size_t)NKVH * S_LEN * HD * 2);
  unsigned short* Vtb = (unsigned short*)alloc((size_t)NKVH * HD * S_LEN * 2);
  float* cosT = (float*)alloc((size_t)S_LEN * NPAIR * 4);
  float* sinT = (float*)alloc((size_t)S_LEN * NPAIR * 4);
  if (off > ws_size) return;

  unsigned short* Ao = hB;  // alias: hidden_bf16 dead after qkv gemm

  f32_to_bf16_all<<<2048, 256, 0, stream>>>(hidden, w_qkv, w_o, hB, wqkvB, woB);
  build_trig<<<(S_LEN * NPAIR + 255) / 256, 256, 0, stream>>>(positions, cosT, sinT);

  gemm8<true, true><<<dim3((QKV_OUT / 128) * 8), 256, 0, stream>>>(
      hB, wqkvB, b_qkv, qkvB, QKV_OUT);

  rope_qk<<<S_LEN, 256, 0, stream>>>(qkvB, cosT, sinT, Qb, Kb);
  v_transpose<<<dim3(S_LEN / 64, NKVH), 256, 0, stream>>>(qkvB, Vtb);

  attn_kernel<<<dim3(512), 256, 0, stream>>>(Qb, Kb, Vtb, Ao);

  gemm160<<<dim3(256), 512, 0, stream>>>(Ao, woB, out);
}

// Round 19
// 446.587 us; speedup vs baseline: 1.0437x; 1.0437x over previous
//
#include <hip/hip_runtime.h>

typedef __attribute__((ext_vector_type(8))) short short8;
typedef __attribute__((ext_vector_type(4))) float f32x4;
typedef __attribute__((ext_vector_type(16))) float f32x16;
typedef __attribute__((ext_vector_type(4))) unsigned short ushort4v;
typedef __attribute__((ext_vector_type(4))) unsigned u32x4;

#define S_LEN 2048
#define E_DIM 5120
#define NH 32
#define NKVH 8
#define HD 160
#define QKV_OUT (NH*HD + 2*NKVH*HD)   // 7680
#define NPAIR 20
#define ROT_D 40

__device__ __forceinline__ unsigned short f2b(float f) {
  unsigned u = __builtin_bit_cast(unsigned, f);
  u += 0x7fffu + ((u >> 16) & 1u);
  return (unsigned short)(u >> 16);
}
__device__ __forceinline__ float b2f(unsigned short b) {
  return __builtin_bit_cast(float, ((unsigned)b) << 16);
}

typedef const __attribute__((address_space(1))) unsigned gu32;
typedef __attribute__((address_space(3))) unsigned lu32;
__device__ __forceinline__ void gll16(const void* g, void* l) {
  __builtin_amdgcn_global_load_lds((gu32*)g, (lu32*)l, 16, 0, 0);
}
#define MFMA16(a, b, c) __builtin_amdgcn_mfma_f32_16x16x32_bf16(a, b, c, 0, 0, 0)
#define MFMA32(a, b, c) __builtin_amdgcn_mfma_f32_32x32x16_bf16(a, b, c, 0, 0, 0)
#define SBAR() asm volatile("s_barrier" ::: "memory")

// ---------------- prep: all three fp32 -> bf16 converts in ONE dispatch ----------------
__device__ __forceinline__ void cvt_seg(const float* __restrict__ in,
                                        unsigned short* __restrict__ out,
                                        long n4, long i0, long stride) {
  for (long i = i0; i < n4; i += stride) {
    float4 v = ((const float4*)in)[i];
    ushort4v o = { f2b(v.x), f2b(v.y), f2b(v.z), f2b(v.w) };
    ((ushort4v*)out)[i] = o;
  }
}
__global__ __launch_bounds__(256) void f32_to_bf16_all(const float* __restrict__ h,
                                                       const float* __restrict__ wq,
                                                       const float* __restrict__ wo,
                                                       unsigned short* __restrict__ hB,
                                                       unsigned short* __restrict__ wqB,
                                                       unsigned short* __restrict__ woB) {
  long i0 = (long)blockIdx.x * blockDim.x + threadIdx.x;
  long stride = (long)gridDim.x * blockDim.x;
  cvt_seg(h, hB, (long)S_LEN * E_DIM / 4, i0, stride);
  cvt_seg(wq, wqB, (long)QKV_OUT * E_DIM / 4, i0, stride);
  cvt_seg(wo, woB, (long)E_DIM * E_DIM / 4, i0, stride);
}

// ---------------- prep: cos/sin tables ----------------
__global__ __launch_bounds__(256) void build_trig(const int* __restrict__ positions,
                                                  float* __restrict__ cosT,
                                                  float* __restrict__ sinT) {
  int idx = blockIdx.x * blockDim.x + threadIdx.x;
  if (idx >= S_LEN * NPAIR) return;
  int s = idx / NPAIR, i = idx - s * NPAIR;
  float inv = powf(10000.0f, -(float)i / (float)NPAIR);
  float f = (float)positions[s] * inv;
  cosT[idx] = cosf(f);
  sinT[idx] = sinf(f);
}

// ---------------- 256x256 2-phase bf16 NT GEMM (r13/r17-proven: reads-first, LDS-staged) ----------------
// P1 {read A0(8)+B0(4)+B1(4); stage A1(t+1)->db^1; 32 MFMA (Q00,Q01); SBAR}
// P2 {read A1(8); stage A0/B0/B1(t+2)->db; 32 MFMA (Q11,Q10); vmcnt(6); SBAR}
// Lessons: stage-first -30% (r12); A-direct gathers -2.2x (r15); BK=32 2-blk/CU
// -15% via half-bank-ring swizzle conflicts (r18). This structure is the local
// optimum of the explored family (4ph 41% / thin 44% / 2ph 45% MfmaUtil).
template <bool BIAS, bool OUT_BF16>
__global__ __launch_bounds__(512, 2) void gemm8(const unsigned short* __restrict__ A,
                                                const unsigned short* __restrict__ B,
                                                const float* __restrict__ bias,
                                                void* __restrict__ Cp,
                                                int N) {
  constexpr int K = E_DIM;
  constexpr int NT = K / 64;
  int bid = blockIdx.x;
  int bm = bid & 7, bn = bid >> 3;
  int tid = threadIdx.x;
  int w = tid >> 6, l = tid & 63;
  int g = l >> 4, c = l & 15;
  int wm = w >> 2, wn = w & 3;

  __shared__ __align__(16) unsigned short LA[2][2][8192];  // 64KB
  __shared__ __align__(16) unsigned short LB[2][2][8192];  // 64KB

  f32x4 acc[8][4];
#pragma unroll
  for (int i = 0; i < 8; ++i)
#pragma unroll
    for (int j = 0; j < 4; ++j) acc[i][j] = f32x4{0.f, 0.f, 0.f, 0.f};

  int uU[2] = {tid, 512 + tid};
  const unsigned short* Ag[2];
  const unsigned short* Bg[2];
#pragma unroll
  for (int j = 0; j < 2; ++j) {
    int u = uU[j];
    int wmG = u >> 9, rlA = (u >> 3) & 63, sl = u & 7;
    Ag[j] = A + (size_t)(bm * 256 + wmG * 128 + rlA) * K + (sl ^ (rlA & 7)) * 8;
    int wnG = u >> 8, rlB = (u >> 3) & 31;
    Bg[j] = B + (size_t)(bn * 256 + wnG * 64 + rlB) * K + (sl ^ (rlB & 7)) * 8;
  }

  auto stageA = [&](int t, int rg, int db) {
#pragma unroll
    for (int j = 0; j < 2; ++j)
      gll16(Ag[j] + (size_t)rg * 64 * K + t * 64, (char*)&LA[db][rg][0] + uU[j] * 16);
  };
  auto stageB = [&](int t, int cg, int db) {
#pragma unroll
    for (int j = 0; j < 2; ++j)
      gll16(Bg[j] + (size_t)cg * 32 * K + t * 64, (char*)&LB[db][cg][0] + uU[j] * 16);
  };

  int aA = wm * 4096 + c * 64;
  int bB = wn * 2048 + c * 64;
  int s0 = (g ^ (c & 7)) * 8;
  int s1 = ((4 + g) ^ (c & 7)) * 8;

  short8 a[8], b0[4], b1[4];

  stageA(0, 0, 0); stageB(0, 0, 0); stageB(0, 1, 0); stageA(0, 1, 0);
  stageA(1, 0, 1); stageB(1, 0, 1); stageB(1, 1, 1);
  asm volatile("s_waitcnt vmcnt(6)" ::: "memory");
  SBAR();

  for (int t = 0; t < NT; ++t) {
    int db = t & 1;
    const unsigned short* la0 = &LA[db][0][0];
    const unsigned short* la1 = &LA[db][1][0];
    const unsigned short* lb0 = &LB[db][0][0];
    const unsigned short* lb1 = &LB[db][1][0];
    bool tail = (t + 2 >= NT);

    // ---- P1: reads A0+B0+B1 (16); stage A1(t+1)->db^1; MFMA Q00+Q01 (32); SBAR
#pragma unroll
    for (int fm = 0; fm < 4; ++fm) {
      a[2 * fm + 0] = *(const short8*)&la0[aA + fm * 1024 + s0];
      a[2 * fm + 1] = *(const short8*)&la0[aA + fm * 1024 + s1];
    }
#pragma unroll
    for (int fn = 0; fn < 2; ++fn) {
      b0[2 * fn + 0] = *(const short8*)&lb0[bB + fn * 1024 + s0];
      b0[2 * fn + 1] = *(const short8*)&lb0[bB + fn * 1024 + s1];
      b1[2 * fn + 0] = *(const short8*)&lb1[bB + fn * 1024 + s0];
      b1[2 * fn + 1] = *(const short8*)&lb1[bB + fn * 1024 + s1];
    }
    if (t + 1 < NT) stageA(t + 1, 1, db ^ 1);
    __builtin_amdgcn_s_setprio(1);
#pragma unroll
    for (int fm = 0; fm < 4; ++fm)
#pragma unroll
      for (int fn = 0; fn < 2; ++fn) {
        acc[fm][fn] = MFMA16(a[2 * fm + 0], b0[2 * fn + 0], acc[fm][fn]);
        acc[fm][fn] = MFMA16(a[2 * fm + 1], b0[2 * fn + 1], acc[fm][fn]);
        acc[fm][fn + 2] = MFMA16(a[2 * fm + 0], b1[2 * fn + 0], acc[fm][fn + 2]);
        acc[fm][fn + 2] = MFMA16(a[2 * fm + 1], b1[2 * fn + 1], acc[fm][fn + 2]);
      }
    __builtin_amdgcn_s_setprio(0);
    SBAR();

    // ---- P2: reads A1 (8); stage A0/B0/B1(t+2)->db; MFMA Q11+Q10 (32); vmcnt; SBAR
#pragma unroll
    for (int fm = 0; fm < 4; ++fm) {
      a[2 * fm + 0] = *(const short8*)&la1[aA + fm * 1024 + s0];
      a[2 * fm + 1] = *(const short8*)&la1[aA + fm * 1024 + s1];
    }
    if (!tail) {
      stageA(t + 2, 0, db);
      stageB(t + 2, 0, db);
      stageB(t + 2, 1, db);
    }
    __builtin_amdgcn_s_setprio(1);
#pragma unroll
    for (int fm = 0; fm < 4; ++fm)
#pragma unroll
      for (int fn = 0; fn < 2; ++fn) {
        acc[fm + 4][fn + 2] = MFMA16(a[2 * fm + 0], b1[2 * fn + 0], acc[fm + 4][fn + 2]);
        acc[fm + 4][fn + 2] = MFMA16(a[2 * fm + 1], b1[2 * fn + 1], acc[fm + 4][fn + 2]);
        acc[fm + 4][fn] = MFMA16(a[2 * fm + 0], b0[2 * fn + 0], acc[fm + 4][fn]);
        acc[fm + 4][fn] = MFMA16(a[2 * fm + 1], b0[2 * fn + 1], acc[fm + 4][fn]);
      }
    __builtin_amdgcn_s_setprio(0);
    if (tail)
      asm volatile("s_waitcnt vmcnt(0)" ::: "memory");
    else
      asm volatile("s_waitcnt vmcnt(6)" ::: "memory");
    SBAR();
  }

  // ---- epilogue
#pragma unroll
  for (int FN = 0; FN < 4; ++FN) {
    int n = bn * 256 + wn * 64 + FN * 16 + c;
    float bv = BIAS ? bias[n] : 0.f;
#pragma unroll
    for (int FM = 0; FM < 8; ++FM) {
#pragma unroll
      for (int r = 0; r < 4; ++r) {
        int m = bm * 256 + wm * 128 + FM * 16 + 4 * g + r;
        float v = acc[FM][FN][r] + bv;
        if (OUT_BF16)
          ((unsigned short*)Cp)[(size_t)m * N + n] = f2b(v);
        else
          ((float*)Cp)[(size_t)m * N + n] = v;
      }
    }
  }
}

// ---------------- 256x160 2-phase bf16 NT GEMM (r13-proven, unchanged) ----------------
__global__ __launch_bounds__(512, 2) void gemm160(const unsigned short* __restrict__ A,
                                                  const unsigned short* __restrict__ B,
                                                  float* __restrict__ C) {
  constexpr int K = E_DIM;
  constexpr int NT = K / 64;
  int bid = blockIdx.x;
  int bm = bid & 7, bn = bid >> 3;
  int tid = threadIdx.x;
  int w = tid >> 6, l = tid & 63;
  int g = l >> 4, c = l & 15;
  int wm = w >> 1, wn = w & 1;

  __shared__ __align__(16) unsigned short LA[2][2][8192];   // 64KB
  __shared__ __align__(16) unsigned short LB[2][20 * 512];  // 40KB

  f32x4 acc[4][5];
#pragma unroll
  for (int i = 0; i < 4; ++i)
#pragma unroll
    for (int j = 0; j < 5; ++j) acc[i][j] = f32x4{0.f, 0.f, 0.f, 0.f};

  int uU[2] = {tid, 512 + tid};
  const unsigned short* Ag[2];
#pragma unroll
  for (int j = 0; j < 2; ++j) {
    int u = uU[j];
    int wmG = u >> 9, rlA = (u >> 3) & 63, sl = u & 7;
    Ag[j] = A + (size_t)(bm * 256 + wmG * 128 + rlA) * K + (sl ^ (rlA & 7)) * 8;
  }
  auto stageA = [&](int t, int rg, int db) {
#pragma unroll
    for (int j = 0; j < 2; ++j)
      gll16(Ag[j] + (size_t)rg * 64 * K + t * 64, (char*)&LA[db][rg][0] + uU[j] * 16);
  };

  int rowin = l >> 3, slb = l & 7;
  int swz = (slb ^ rowin) * 8;
  int chN01 = (w < 4) ? w : 6 + w;
  int chN23 = (w < 4) ? 4 + w : 10 + w;
  int chN4 = (w < 2) ? 8 + w : 16 + w;
  const unsigned short* srcN01 = B + (size_t)(bn * 160 + chN01 * 8 + rowin) * K + swz;
  const unsigned short* srcN23 = B + (size_t)(bn * 160 + chN23 * 8 + rowin) * K + swz;
  const unsigned short* srcN4 = B + (size_t)(bn * 160 + ((w < 4) ? chN4 * 8 : 0) + rowin) * K + swz;
  auto stB = [&](const unsigned short* src, int ch, int t, int db) {
    gll16(src + t * 64, (char*)&LB[db][0] + ch * 1024 + l * 16);
  };

  int rgA = wm & 1;
  int aA = ((wm >> 1) * 64 + c) * 64;
  int bB = (wn * 80 + c) * 64;
  int s0 = (g ^ (c & 7)) * 8;
  int s1 = ((4 + g) ^ (c & 7)) * 8;

  short8 a[8], b01[4], b23[4], bn4[2];

  stageA(0, 0, 0); stageA(0, 1, 0);
  stB(srcN01, chN01, 0, 0); stB(srcN23, chN23, 0, 0);
  if (w < 4) stB(srcN4, chN4, 0, 0);
  stageA(1, 0, 1); stageA(1, 1, 1);
  stB(srcN01, chN01, 1, 1); stB(srcN23, chN23, 1, 1);
  asm volatile("s_waitcnt vmcnt(0)" ::: "memory");
  SBAR();

  for (int t = 0; t < NT; ++t) {
    int db = t & 1;
    const unsigned short* la = &LA[db][rgA][0];
    const unsigned short* lb = &LB[db][0];
    bool tail = (t + 2 >= NT);

    // ---- P1
#pragma unroll
    for (int fm = 0; fm < 4; ++fm) {
      a[2 * fm + 0] = *(const short8*)&la[aA + fm * 1024 + s0];
      a[2 * fm + 1] = *(const short8*)&la[aA + fm * 1024 + s1];
    }
#pragma unroll
    for (int fn = 0; fn < 2; ++fn) {
      b01[2 * fn + 0] = *(const short8*)&lb[bB + fn * 1024 + s0];
      b01[2 * fn + 1] = *(const short8*)&lb[bB + fn * 1024 + s1];
      b23[2 * fn + 0] = *(const short8*)&lb[bB + (2 + fn) * 1024 + s0];
      b23[2 * fn + 1] = *(const short8*)&lb[bB + (2 + fn) * 1024 + s1];
    }
    if (t + 1 < NT && w < 4) stB(srcN4, chN4, t + 1, db ^ 1);
    __builtin_amdgcn_s_setprio(1);
#pragma unroll
    for (int fm = 0; fm < 4; ++fm)
#pragma unroll
      for (int fn = 0; fn < 2; ++fn) {
        acc[fm][fn] = MFMA16(a[2 * fm + 0], b01[2 * fn + 0], acc[fm][fn]);
        acc[fm][fn] = MFMA16(a[2 * fm + 1], b01[2 * fn + 1], acc[fm][fn]);
        acc[fm][fn + 2] = MFMA16(a[2 * fm + 0], b23[2 * fn + 0], acc[fm][fn + 2]);
        acc[fm][fn + 2] = MFMA16(a[2 * fm + 1], b23[2 * fn + 1], acc[fm][fn + 2]);
      }
    __builtin_amdgcn_s_setprio(0);
    SBAR();

    // ---- P2
    bn4[0] = *(const short8*)&lb[bB + 4 * 1024 + s0];
    bn4[1] = *(const short8*)&lb[bB + 4 * 1024 + s1];
    if (!tail) {
      stageA(t + 2, 0, db); stageA(t + 2, 1, db);
      stB(srcN01, chN01, t + 2, db);
      stB(srcN23, chN23, t + 2, db);
    }
    __builtin_amdgcn_s_setprio(1);
#pragma unroll
    for (int fm = 0; fm < 4; ++fm) {
      acc[fm][4] = MFMA16(a[2 * fm + 0], bn4[0], acc[fm][4]);
      acc[fm][4] = MFMA16(a[2 * fm + 1], bn4[1], acc[fm][4]);
    }
    __builtin_amdgcn_s_setprio(0);
    if (tail)
      asm volatile("s_waitcnt vmcnt(0)" ::: "memory");
    else
      asm volatile("s_waitcnt vmcnt(6)" ::: "memory");
    SBAR();
  }

  // ---- epilogue (fp32)
#pragma unroll
  for (int fn = 0; fn < 5; ++fn) {
    int n = bn * 160 + wn * 80 + fn * 16 + c;
#pragma unroll
    for (int fm = 0; fm < 4; ++fm) {
#pragma unroll
      for (int r = 0; r < 4; ++r) {
        int m = bm * 256 + wm * 64 + fm * 16 + 4 * g + r;
        C[(size_t)m * E_DIM + n] = acc[fm][fn][r];
      }
    }
  }
}

// ---------------- rope (Q,K only; vectorized non-rot copy) ----------------
__global__ __launch_bounds__(256) void rope_qk(const unsigned short* __restrict__ qkv,
                                               const float* __restrict__ cosT,
                                               const float* __restrict__ sinT,
                                               unsigned short* __restrict__ Q,
                                               unsigned short* __restrict__ K) {
  int s = blockIdx.x;
  int tid = threadIdx.x;
  const unsigned short* row = qkv + (size_t)s * QKV_OUT;
  const float* cs = cosT + s * NPAIR;
  const float* sn = sinT + s * NPAIR;
  for (int p = tid; p < 40 * NPAIR; p += 256) {
    int head = p / NPAIR, i = p - head * NPAIR;
    float x1 = b2f(row[head * HD + i]);
    float x2 = b2f(row[head * HD + i + NPAIR]);
    float o1 = x1 * cs[i] - x2 * sn[i];
    float o2 = x2 * cs[i] + x1 * sn[i];
    unsigned short* dst = (head < NH) ? (Q + ((size_t)head * S_LEN + s) * HD)
                                      : (K + ((size_t)(head - NH) * S_LEN + s) * HD);
    dst[i] = f2b(o1);
    dst[i + NPAIR] = f2b(o2);
  }
  for (int u = tid; u < 40 * 15; u += 256) {
    int head = u / 15;
    int d8 = ROT_D + (u - head * 15) * 8;
    short8 v = *(const short8*)(row + head * HD + d8);
    unsigned short* dst = (head < NH) ? (Q + ((size_t)head * S_LEN + s) * HD)
                                      : (K + ((size_t)(head - NH) * S_LEN + s) * HD);
    *(short8*)(dst + d8) = v;
  }
}

// ---------------- V transpose: qkv -> Vt[kvh][d][s] ----------------
__global__ __launch_bounds__(256) void v_transpose(const unsigned short* __restrict__ qkv,
                                                   unsigned short* __restrict__ Vt) {
  int st = blockIdx.x;
  int kvh = blockIdx.y;
  int tid = threadIdx.x;
  __shared__ __align__(16) unsigned short T[64][168];
  const unsigned short* src = qkv + (size_t)(st * 64) * QKV_OUT + NH * HD + NKVH * HD + kvh * HD;
#pragma unroll
  for (int i = 0; i < 5; ++i) {
    int u = tid + i * 256;
    int r = u / 20, sl = u - r * 20;
    int4 val = *(const int4*)(src + (size_t)r * QKV_OUT + sl * 8);
    *(int4*)((char*)&T[r][0] + sl * 16) = val;
  }
  __syncthreads();
  unsigned short* dst = Vt + (size_t)kvh * HD * S_LEN + st * 64;
#pragma unroll
  for (int i = 0; i < 5; ++i) {
    int u = tid + i * 256;
    int d = u >> 3, sc = u & 7;
    unsigned short tmp[8];
#pragma unroll
    for (int j = 0; j < 8; ++j) tmp[j] = T[sc * 8 + j][d];
    *(int4*)(dst + (size_t)d * S_LEN + sc * 8) = *(const int4*)tmp;
  }
}

// ---------------- flash causal GQA attention, 32x32 MFMA, in-register P ----------------
// kvh = bid&7 == XCD (K/V L2-resident); strip = sidx<32 ? 63-sidx : sidx-32 so
// co-resident pair (bid, bid+256) is complementary (65 tiles per CU).
__global__ __launch_bounds__(256, 1) void attn_kernel(const unsigned short* __restrict__ Q,
                                                      const unsigned short* __restrict__ K,
                                                      const unsigned short* __restrict__ Vt,
                                                      unsigned short* __restrict__ Ao) {
  int bid = blockIdx.x;
  int kvh = bid & 7;
  int sidx = bid >> 3;
  int strip = (sidx < 32) ? (63 - sidx) : (sidx - 32);
  int nt = strip + 1;
  int qbase = strip * 32;
  int tid = threadIdx.x;
  int w = tid >> 6, l = tid & 63;
  int lo5 = l & 31, hi = l >> 5;
  int h = kvh * 4 + w;

  __shared__ __align__(16) unsigned short KL[2][10 * 512];
  __shared__ __align__(16) unsigned short VL[2][10 * 512];

  const unsigned short* kg = K + (size_t)kvh * S_LEN * HD;
  const unsigned short* vg = Vt + (size_t)kvh * HD * S_LEN;
  const unsigned short* qg = Q + ((size_t)h * S_LEN + qbase + lo5) * HD;

  short8 qf[10];
#pragma unroll
  for (int f = 0; f < 10; ++f) qf[f] = *(const short8*)(qg + f * 16 + hi * 8);

  auto STAGE = [&](int t, int buf) {
#pragma unroll
    for (int i = 0; i < 5; ++i) {
      int cc = w * 5 + i;
      if (cc < 10) {
        gll16(kg + ((size_t)(t * 32) + lo5) * HD + cc * 16 + hi * 8,
              (void*)&KL[buf][cc * 512]);
      } else {
        int m = cc - 10;
        int dblk = m >> 1, half = m & 1;
        gll16(vg + (size_t)(dblk * 32 + lo5) * S_LEN + t * 32 + half * 16 + hi * 8,
              (void*)&VL[buf][m * 512]);
      }
    }
  };

  const float sm_scale = 0.07905694150420949f;  // 160^-0.5
  f32x16 acc[5];
#pragma unroll
  for (int d = 0; d < 5; ++d)
#pragma unroll
    for (int r = 0; r < 16; ++r) acc[d][r] = 0.f;
  float l_run = 0.f;

  STAGE(0, 0);
  if (nt > 1) STAGE(1, 1);

#pragma unroll 1
  for (int t = 0; t < nt; ++t) {
    int buf = t & 1;
    if (t + 1 < nt)
      asm volatile("s_waitcnt vmcnt(5)" ::: "memory");
    else
      asm volatile("s_waitcnt vmcnt(0)" ::: "memory");
    SBAR();

    f32x16 S;
#pragma unroll
    for (int r = 0; r < 16; ++r) S[r] = 0.f;
    __builtin_amdgcn_s_setprio(1);
#pragma unroll
    for (int f = 0; f < 10; ++f) {
      short8 kf = *(const short8*)&KL[buf][f * 512 + l * 8];
      S = MFMA32(kf, qf[f], S);
    }
    __builtin_amdgcn_s_setprio(0);

    float e[16];
    float rsum = 0.f;
    if (t == nt - 1) {
#pragma unroll
      for (int r = 0; r < 16; ++r) {
        int kvloc = (r & 3) + 8 * (r >> 2) + 4 * hi;
        float x = (kvloc <= lo5) ? S[r] * sm_scale : -1e30f;
        e[r] = __expf(x);
        rsum += e[r];
      }
    } else {
#pragma unroll
      for (int r = 0; r < 16; ++r) {
        e[r] = __expf(S[r] * sm_scale);
        rsum += e[r];
      }
    }
    rsum += __shfl_xor(rsum, 32);
    l_run += rsum;

    unsigned xp[8];
#pragma unroll
    for (int i = 0; i < 8; ++i)
      asm("v_cvt_pk_bf16_f32 %0, %1, %2" : "=v"(xp[i]) : "v"(e[2 * i]), "v"(e[2 * i + 1]));
    asm volatile("v_permlane32_swap_b32 %0, %1" : "+v"(xp[0]), "+v"(xp[2]));
    asm volatile("v_permlane32_swap_b32 %0, %1" : "+v"(xp[1]), "+v"(xp[3]));
    asm volatile("v_permlane32_swap_b32 %0, %1" : "+v"(xp[4]), "+v"(xp[6]));
    asm volatile("v_permlane32_swap_b32 %0, %1" : "+v"(xp[5]), "+v"(xp[7]));
    u32x4 w0 = {xp[0], xp[1], xp[2], xp[3]};
    u32x4 w1 = {xp[4], xp[5], xp[6], xp[7]};
    short8 pa0 = __builtin_bit_cast(short8, w0);
    short8 pa1 = __builtin_bit_cast(short8, w1);

    __builtin_amdgcn_s_setprio(1);
#pragma unroll
    for (int dblk = 0; dblk < 5; ++dblk) {
      short8 v0 = *(const short8*)&VL[buf][(2 * dblk + 0) * 512 + l * 8];
      short8 v1 = *(const short8*)&VL[buf][(2 * dblk + 1) * 512 + l * 8];
      acc[dblk] = MFMA32(pa0, v0, acc[dblk]);
      acc[dblk] = MFMA32(pa1, v1, acc[dblk]);
    }
    __builtin_amdgcn_s_setprio(0);
    SBAR();
    if (t + 2 < nt) STAGE(t + 2, buf);
  }

  float rinv = 1.f / l_run;
  float ri[16];
#pragma unroll
  for (int r = 0; r < 16; ++r) ri[r] = __shfl(rinv, (r & 3) + 8 * (r >> 2) + 4 * hi);
#pragma unroll
  for (int dblk = 0; dblk < 5; ++dblk)
#pragma unroll
    for (int r = 0; r < 16; ++r) {
      int q = (r & 3) + 8 * (r >> 2) + 4 * hi;
      Ao[(size_t)(qbase + q) * E_DIM + h * HD + dblk * 32 + lo5] = f2b(acc[dblk][r] * ri[r]);
    }
}

// ---------------- launch ----------------
extern "C" void kernel_launch(void* const* d_in, const int* in_sizes, int n_in,
                              void* d_out, int out_size, void* d_ws, size_t ws_size,
                              hipStream_t stream) {
  const float* hidden = (const float*)d_in[0];
  const int* positions = (const int*)d_in[1];
  const float* w_qkv = (const float*)d_in[2];
  const float* b_qkv = (const float*)d_in[3];
  const float* w_o = (const float*)d_in[4];
  float* out = (float*)d_out;

  char* ws = (char*)d_ws;
  size_t off = 0;
  auto alloc = [&](size_t bytes) {
    void* p = ws + off;
    off += (bytes + 255) & ~(size_t)255;
    return p;
  };
  unsigned short* hB = (unsigned short*)alloc((size_t)S_LEN * E_DIM * 2);
  unsigned short* wqkvB = (unsigned short*)alloc((size_t)QKV_OUT * E_DIM * 2);
  unsigned short* woB = (unsigned short*)alloc((size_t)E_DIM * E_DIM * 2);
  unsigned short* qkvB = (unsigned short*)alloc((size_t)S_LEN * QKV_OUT * 2);
  unsigned short* Qb = (unsigned short*)alloc((size_t)NH * S_LEN * HD * 2);
  unsigned short* Kb = (unsigned short*)alloc((size_t)NKVH * S_LEN * HD * 2);
  unsigned short* Vtb = (unsigned short*)alloc((size_t)NKVH * HD * S_LEN * 2);
  float* cosT = (float*)alloc((size_t)S_LEN * NPAIR * 4);
  float* sinT = (float*)alloc((size_t)S_LEN * NPAIR * 4);
  if (off > ws_size) return;

  unsigned short* Ao = hB;  // alias: hidden_bf16 dead after qkv gemm

  f32_to_bf16_all<<<2048, 256, 0, stream>>>(hidden, w_qkv, w_o, hB, wqkvB, woB);
  build_trig<<<(S_LEN * NPAIR + 255) / 256, 256, 0, stream>>>(positions, cosT, sinT);

  gemm8<true, true><<<dim3((QKV_OUT / 256) * 8), 512, 0, stream>>>(
      hB, wqkvB, b_qkv, qkvB, QKV_OUT);

  rope_qk<<<S_LEN, 256, 0, stream>>>(qkvB, cosT, sinT, Qb, Kb);
  v_transpose<<<dim3(S_LEN / 64, NKVH), 256, 0, stream>>>(qkvB, Vtb);

  attn_kernel<<<dim3(512), 256, 0, stream>>>(Qb, Kb, Vtb, Ao);

  gemm160<<<dim3(256), 512, 0, stream>>>(Ao, woB, out);
}